// Round 1
// 434.104 us; speedup vs baseline: 1.1557x; 1.1557x over previous
//
#include <hip/hip_runtime.h>
#include <hip/hip_bf16.h>

// Problem constants (match reference) — ALL float inputs/outputs are FP32.
#define T_TOK 4096
#define D_DIM 768
#define L_SPAN 10
#define H_HID 150
#define N_SPANS (T_TOK * L_SPAN)   // 40960
#define GDIM 2304                  // 3*D
#define YCOLS 480                  // stored Y: groups 1..3 only (attn fused)
#define NC16 40                    // 640 output cols / 16 per MFMA tile
#define KK24 24                    // 768 / 32 k-steps

typedef __attribute__((ext_vector_type(8))) short bf16x8;  // 8 bf16 = 4 VGPRs
typedef __attribute__((ext_vector_type(4))) float f32x4;   // native 16B vector

using bf16_t = __hip_bfloat16;

static __device__ __forceinline__ short f2b(float x) {
  __hip_bfloat16 h = __float2bfloat16(x);  // RNE
  short r;
  __builtin_memcpy(&r, &h, 2);
  return r;
}

// ---------------------------------------------------------------------------
// K0: build FRAGMENT-MAJOR packed bf16 weights.
//   Fragment slot s = (c16*24 + kk)*64 + lane holds the 8 bf16 that lane
//   `lane` feeds to MFMA 16x16x32 for col-tile c16, k-step kk:
//     col j = c16*16 + (lane&15), k = (lane>>4)*8 + kk*32 + e.
//   => K1's B-loads become perfectly coalesced 1 KB/wave instructions.
//   Source col j: group g=j/160, cj=j%160 (valid iff cj<150):
//     g==0: W_a1[k][cj]   g>=1: W_m1[k + (g-1)*768][cj]
// ---------------------------------------------------------------------------
__global__ void prep_kernel(const float* __restrict__ W_a1,
                            const float* __restrict__ W_m1,
                            bf16_t* __restrict__ Bp) {
  const int total = NC16 * KK24 * 64;  // 61440 fragment slots
  for (int s = blockIdx.x * blockDim.x + threadIdx.x; s < total;
       s += gridDim.x * blockDim.x) {
    const int c16 = s / (KK24 * 64);
    const int rem = s - c16 * (KK24 * 64);
    const int kk = rem >> 6;
    const int l = rem & 63;
    const int j = c16 * 16 + (l & 15);          // output col 0..639
    const int k0 = ((l >> 4) << 3) + kk * 32;   // k base 0..760
    const int grp = j / 160;
    const int cj = j - grp * 160;
    bf16x8 out;
#pragma unroll
    for (int e = 0; e < 8; ++e) {
      float v = 0.f;
      if (cj < H_HID) {
        const int k = k0 + e;
        v = (grp == 0) ? W_a1[k * H_HID + cj]
                       : W_m1[(k + (grp - 1) * D_DIM) * H_HID + cj];
      }
      out[e] = f2b(v);
    }
    ((bf16x8*)Bp)[s] = out;  // consecutive threads -> consecutive 16B: coalesced
  }
}

// ---------------------------------------------------------------------------
// K1: token GEMM (fp32 in, bf16 MFMA).  Block = 16 token rows, 8 waves
//   (512 thr -> 2 waves/SIMD for latency hiding; old version had 1/SIMD).
//   A staged once as bf16 in LDS (padded stride 776 -> 2-way bank = free).
//   Wave w owns col-tiles c16 = w*5..w*5+4 (80 cols):
//     waves 0..1: cols 0..159 (attn FFNN) -> partial relu-dot, LDS-combined
//     waves 2..7: cols 160..639 -> Y[T][480] fp32
//   MFMA 16x16x32 bf16, C/D layout (m89): col=lane&15, row=quad*4+reg.
// ---------------------------------------------------------------------------
__global__ __launch_bounds__(512) void token_gemm_kernel(
    const float* __restrict__ E, const bf16_t* __restrict__ Bp,
    float* __restrict__ Y, float* __restrict__ attns,
    const float* __restrict__ b_a1, const float* __restrict__ W_a2,
    const float* __restrict__ b_a2) {
  __shared__ __align__(16) bf16_t As[16][776];  // 24832 B, +16B row pad
  __shared__ float part[2][16];

  const int tid = threadIdx.x;
  const int wave = tid >> 6;
  const int lane = tid & 63;
  const int m16 = lane & 15;
  const int quad = lane >> 4;
  const int rowBase = blockIdx.x * 16;

  // ---- stage A: 16 rows x 768 fp32 -> bf16 LDS (coalesced 32B/thread) ----
  for (int idx = tid; idx < 16 * 96; idx += 512) {
    const int r = idx / 96;
    const int c8 = idx - r * 96;
    const float* src = E + (long)(rowBase + r) * D_DIM + c8 * 8;
    const f32x4 f0 = *(const f32x4*)src;
    const f32x4 f1 = *(const f32x4*)(src + 4);
    bf16x8 a;
    a[0] = f2b(f0.x); a[1] = f2b(f0.y); a[2] = f2b(f0.z); a[3] = f2b(f0.w);
    a[4] = f2b(f1.x); a[5] = f2b(f1.y); a[6] = f2b(f1.z); a[7] = f2b(f1.w);
    *(bf16x8*)&As[r][c8 * 8] = a;
  }
  __syncthreads();

  f32x4 acc[5];
#pragma unroll
  for (int nt = 0; nt < 5; ++nt) acc[nt] = (f32x4){0.f, 0.f, 0.f, 0.f};

  for (int kk = 0; kk < KK24; ++kk) {
    const bf16x8 a = *(const bf16x8*)&As[m16][quad * 8 + kk * 32];
#pragma unroll
    for (int nt = 0; nt < 5; ++nt) {
      // coalesced: lane-consecutive 16B chunks of the packed fragment
      const bf16x8 b = *(const bf16x8*)(
          Bp + ((long)((wave * 5 + nt) * KK24 + kk) * 64 + lane) * 8);
      acc[nt] = __builtin_amdgcn_mfma_f32_16x16x32_bf16(a, b, acc[nt], 0, 0, 0);
    }
  }

  if (wave < 2) {
    // attn-FFNN partial epilogue over this wave's 80 cols
    float s[4] = {0.f, 0.f, 0.f, 0.f};
#pragma unroll
    for (int nt = 0; nt < 5; ++nt) {
      const int c = (wave * 5 + nt) * 16 + m16;
      float b1c = 0.f, w2c = 0.f;
      if (c < H_HID) { b1c = b_a1[c]; w2c = W_a2[c]; }
#pragma unroll
      for (int r = 0; r < 4; ++r) {
        const float h = acc[nt][r] + b1c;
        s[r] += (h > 0.f ? h : 0.f) * w2c;
      }
    }
#pragma unroll
    for (int m = 1; m <= 8; m <<= 1) {
#pragma unroll
      for (int r = 0; r < 4; ++r) s[r] += __shfl_xor(s[r], m, 64);
    }
    if (m16 == 0) {
#pragma unroll
      for (int r = 0; r < 4; ++r) part[wave][quad * 4 + r] = s[r];
    }
  } else {
    const int c0 = wave * 80 - 160;  // Y col base for this wave
#pragma unroll
    for (int nt = 0; nt < 5; ++nt) {
#pragma unroll
      for (int r = 0; r < 4; ++r) {
        Y[(long)(rowBase + quad * 4 + r) * YCOLS + c0 + nt * 16 + m16] =
            acc[nt][r];
      }
    }
  }
  __syncthreads();
  if (tid < 16) attns[rowBase + tid] = part[0][tid] + part[1][tid] + b_a2[0];
}

// ---------------------------------------------------------------------------
// K2: one block per start token t.  Wave-specialized, ONE barrier:
//   pre-barrier : threads 0..9 compute softmax weights (attns direct from
//                 global) -> wtsT[o][l]; wave 3 stages Y rows in LDS.
//   post-barrier: waves 0..2 (192 thr): thread owns f32x4 column d.
//                 Pooled: acc[10] registers, 1 embed load feeds all 10 spans
//                 (10x fewer reads than old per-span scheme).  Start/end
//                 copies reload rows (L1/L2-hot).  30 NT f32x4 stores/thread.
//                 wave 3: span scores from Ys.
//   LDS 19.7 KB (was 50.4) -> 8 blocks/CU by LDS; no E stage, no l-unroll
//   register blowup.
// ---------------------------------------------------------------------------
__global__ __launch_bounds__(256) void span_kernel(
    const float* __restrict__ embeds, const int* __restrict__ ends,
    const float* __restrict__ Y, const float* __restrict__ attns,
    const float* __restrict__ b_m1, const float* __restrict__ W_m2,
    const float* __restrict__ b_m2, float* __restrict__ g,
    float* __restrict__ scores) {
  __shared__ __align__(16) float Ys[L_SPAN][YCOLS];  // 19200 B
  __shared__ __align__(16) float wtsT[L_SPAN][12];   // [o][l], padded to 12
  __shared__ int sIE[L_SPAN];

  const int t = blockIdx.x;
  const int tid = threadIdx.x;
  const int wave = tid >> 6;
  const int lane = tid & 63;

  if (wave == 3) {
    // stage Y rows t..t+9 (clamped) — only wave 3 ever reads Ys
    for (int idx = lane; idx < L_SPAN * 120; idx += 64) {
      const int i = idx / 120, dd = idx - i * 120;
      const int r = min(t + i, T_TOK - 1);
      ((f32x4*)Ys)[idx] = ((const f32x4*)(Y + (long)r * YCOLS))[dd];
    }
  }
  if (tid < L_SPAN) {
    float a[L_SPAN];
#pragma unroll
    for (int o = 0; o < L_SPAN; ++o) a[o] = attns[min(t + o, T_TOK - 1)];
    const int ie = ends[t * L_SPAN + tid] - t;  // 0..9
    sIE[tid] = ie;
    float mx = a[0];
    for (int o = 1; o <= ie; ++o) mx = fmaxf(mx, a[o]);
    float den = 0.f;
    for (int o = 0; o <= ie; ++o) den += __expf(a[o] - mx);
    const float inv = 1.f / den;
#pragma unroll
    for (int o = 0; o < L_SPAN; ++o)
      wtsT[o][tid] = (o <= ie) ? __expf(a[o] - mx) * inv : 0.f;
  }
  __syncthreads();

  if (wave < 3) {
    const int d = tid;  // f32x4 column 0..191 (= floats d*4..d*4+3)
    f32x4 acc[L_SPAN];
#pragma unroll
    for (int l = 0; l < L_SPAN; ++l) acc[l] = (f32x4){0.f, 0.f, 0.f, 0.f};

    // pooled: one embed read per (o,d), reused by all 10 spans in registers
#pragma unroll
    for (int o = 0; o < L_SPAN; ++o) {
      const int r = min(t + o, T_TOK - 1);
      const f32x4 e = *(const f32x4*)(embeds + (long)r * D_DIM + d * 4);
      const f32x4 w0 = *(const f32x4*)&wtsT[o][0];
      const f32x4 w4 = *(const f32x4*)&wtsT[o][4];
      const f32x4 w8 = *(const f32x4*)&wtsT[o][8];
      acc[0] += e * w0.x; acc[1] += e * w0.y;
      acc[2] += e * w0.z; acc[3] += e * w0.w;
      acc[4] += e * w4.x; acc[5] += e * w4.y;
      acc[6] += e * w4.z; acc[7] += e * w4.w;
      acc[8] += e * w8.x; acc[9] += e * w8.y;
    }

    const f32x4 e0 = *(const f32x4*)(embeds + (long)t * D_DIM + d * 4);
    float* gbase = g + (long)t * L_SPAN * GDIM + d * 4;
#pragma unroll
    for (int l = 0; l < L_SPAN; ++l) {
      float* go = gbase + (long)l * GDIM;
      const int re = t + sIE[l];  // = ends[t*10+l] <= T-1, no clamp needed
      const f32x4 ee = *(const f32x4*)(embeds + (long)re * D_DIM + d * 4);
      __builtin_nontemporal_store(e0, (f32x4*)go);                // start
      __builtin_nontemporal_store(ee, (f32x4*)(go + D_DIM));      // end
      __builtin_nontemporal_store(acc[l], (f32x4*)(go + 2 * D_DIM));  // pooled
    }
  } else {
    // span scores (wave 3 alone; Ys was written by this wave pre-barrier)
    const float bm2 = b_m2[0];
    for (int l = 0; l < L_SPAN; ++l) {
      const int ie = sIE[l];
      float wl[L_SPAN];
#pragma unroll
      for (int o = 0; o < L_SPAN; ++o) wl[o] = wtsT[o][l];
      float p = 0.f;
      for (int c = lane; c < H_HID; c += 64) {
        float h = Ys[0][c] + Ys[ie][160 + c] + b_m1[c];
#pragma unroll
        for (int o = 0; o < L_SPAN; ++o) h += wl[o] * Ys[o][320 + c];
        p += (h > 0.f ? h : 0.f) * W_m2[c];
      }
#pragma unroll
      for (int m = 1; m <= 32; m <<= 1) p += __shfl_xor(p, m, 64);
      if (lane == 0) scores[t * L_SPAN + l] = p + bm2;
    }
  }
}

// ---------------------------------------------------------------------------
extern "C" void kernel_launch(void* const* d_in, const int* in_sizes, int n_in,
                              void* d_out, int out_size, void* d_ws,
                              size_t ws_size, hipStream_t stream) {
  const float* embeds = (const float*)d_in[0];
  const int* ends = (const int*)d_in[2];
  const float* W_a1 = (const float*)d_in[3];
  const float* b_a1 = (const float*)d_in[4];
  const float* W_a2 = (const float*)d_in[5];
  const float* b_a2 = (const float*)d_in[6];
  const float* W_m1 = (const float*)d_in[7];
  const float* b_m1 = (const float*)d_in[8];
  const float* W_m2 = (const float*)d_in[9];
  const float* b_m2 = (const float*)d_in[10];

  char* ws = (char*)d_ws;
  bf16_t* Bp = (bf16_t*)ws;                    // 640*768*2  =   983,040 B
  float* Y = (float*)(ws + 983040);            // 4096*480*4 = 7,864,320 B
  float* attns = (float*)(ws + 983040 + 7864320);  // 16,384 B

  float* g_out = (float*)d_out;                     // [N][2304]
  float* score_out = g_out + (long)N_SPANS * GDIM;  // [N]

  prep_kernel<<<240, 256, 0, stream>>>(W_a1, W_m1, Bp);
  token_gemm_kernel<<<T_TOK / 16, 512, 0, stream>>>(embeds, Bp, Y, attns,
                                                    b_a1, W_a2, b_a2);
  span_kernel<<<T_TOK, 256, 0, stream>>>(embeds, ends, Y, attns, b_m1, W_m2,
                                         b_m2, g_out, score_out);
}

// Round 2
// 430.467 us; speedup vs baseline: 1.1655x; 1.0084x over previous
//
#include <hip/hip_runtime.h>
#include <hip/hip_bf16.h>

// Problem constants (match reference) — ALL float inputs/outputs are FP32.
#define T_TOK 4096
#define D_DIM 768
#define L_SPAN 10
#define H_HID 150
#define N_SPANS (T_TOK * L_SPAN)   // 40960
#define GDIM 2304                  // 3*D
#define YCOLS 480                  // stored Y: groups 1..3 only (attn fused)
#define NC16 40                    // 640 output cols / 16 per MFMA tile
#define KK24 24                    // 768 / 32 k-steps

typedef __attribute__((ext_vector_type(8))) short bf16x8;  // 8 bf16 = 4 VGPRs
typedef __attribute__((ext_vector_type(4))) float f32x4;   // native 16B vector

using bf16_t = __hip_bfloat16;

static __device__ __forceinline__ short f2b(float x) {
  __hip_bfloat16 h = __float2bfloat16(x);  // RNE
  short r;
  __builtin_memcpy(&r, &h, 2);
  return r;
}

// ---------------------------------------------------------------------------
// K0: build FRAGMENT-MAJOR packed bf16 weights.
//   Fragment slot s = (c16*24 + kk)*64 + lane holds the 8 bf16 that lane
//   `lane` feeds to MFMA 16x16x32 for col-tile c16, k-step kk:
//     col j = c16*16 + (lane&15), k = (lane>>4)*8 + kk*32 + e.
// ---------------------------------------------------------------------------
__global__ void prep_kernel(const float* __restrict__ W_a1,
                            const float* __restrict__ W_m1,
                            bf16_t* __restrict__ Bp) {
  const int total = NC16 * KK24 * 64;  // 61440 fragment slots
  for (int s = blockIdx.x * blockDim.x + threadIdx.x; s < total;
       s += gridDim.x * blockDim.x) {
    const int c16 = s / (KK24 * 64);
    const int rem = s - c16 * (KK24 * 64);
    const int kk = rem >> 6;
    const int l = rem & 63;
    const int j = c16 * 16 + (l & 15);          // output col 0..639
    const int k0 = ((l >> 4) << 3) + kk * 32;   // k base 0..760
    const int grp = j / 160;
    const int cj = j - grp * 160;
    bf16x8 out;
#pragma unroll
    for (int e = 0; e < 8; ++e) {
      float v = 0.f;
      if (cj < H_HID) {
        const int k = k0 + e;
        v = (grp == 0) ? W_a1[k * H_HID + cj]
                       : W_m1[(k + (grp - 1) * D_DIM) * H_HID + cj];
      }
      out[e] = f2b(v);
    }
    ((bf16x8*)Bp)[s] = out;  // consecutive threads -> consecutive 16B
  }
}

// ---------------------------------------------------------------------------
// K1: token GEMM (fp32 in, bf16 MFMA).  Block = 16 token rows, 8 waves.
//   A staged once as bf16 in LDS (padded stride 776 -> 2-way bank = free).
//   Wave w owns col-tiles c16 = w*5..w*5+4 (80 cols):
//     waves 0..1: cols 0..159 (attn FFNN) -> partial relu-dot, LDS-combined
//     waves 2..7: cols 160..639 -> Y[T][480] fp32
//   MFMA 16x16x32 bf16, C/D layout (m89): col=lane&15, row=quad*4+reg.
// ---------------------------------------------------------------------------
__global__ __launch_bounds__(512) void token_gemm_kernel(
    const float* __restrict__ E, const bf16_t* __restrict__ Bp,
    float* __restrict__ Y, float* __restrict__ attns,
    const float* __restrict__ b_a1, const float* __restrict__ W_a2,
    const float* __restrict__ b_a2) {
  __shared__ __align__(16) bf16_t As[16][776];  // 24832 B, +16B row pad
  __shared__ float part[2][16];

  const int tid = threadIdx.x;
  const int wave = tid >> 6;
  const int lane = tid & 63;
  const int m16 = lane & 15;
  const int quad = lane >> 4;
  const int rowBase = blockIdx.x * 16;

  for (int idx = tid; idx < 16 * 96; idx += 512) {
    const int r = idx / 96;
    const int c8 = idx - r * 96;
    const float* src = E + (long)(rowBase + r) * D_DIM + c8 * 8;
    const f32x4 f0 = *(const f32x4*)src;
    const f32x4 f1 = *(const f32x4*)(src + 4);
    bf16x8 a;
    a[0] = f2b(f0.x); a[1] = f2b(f0.y); a[2] = f2b(f0.z); a[3] = f2b(f0.w);
    a[4] = f2b(f1.x); a[5] = f2b(f1.y); a[6] = f2b(f1.z); a[7] = f2b(f1.w);
    *(bf16x8*)&As[r][c8 * 8] = a;
  }
  __syncthreads();

  f32x4 acc[5];
#pragma unroll
  for (int nt = 0; nt < 5; ++nt) acc[nt] = (f32x4){0.f, 0.f, 0.f, 0.f};

  for (int kk = 0; kk < KK24; ++kk) {
    const bf16x8 a = *(const bf16x8*)&As[m16][quad * 8 + kk * 32];
#pragma unroll
    for (int nt = 0; nt < 5; ++nt) {
      const bf16x8 b = *(const bf16x8*)(
          Bp + ((long)((wave * 5 + nt) * KK24 + kk) * 64 + lane) * 8);
      acc[nt] = __builtin_amdgcn_mfma_f32_16x16x32_bf16(a, b, acc[nt], 0, 0, 0);
    }
  }

  if (wave < 2) {
    float s[4] = {0.f, 0.f, 0.f, 0.f};
#pragma unroll
    for (int nt = 0; nt < 5; ++nt) {
      const int c = (wave * 5 + nt) * 16 + m16;
      float b1c = 0.f, w2c = 0.f;
      if (c < H_HID) { b1c = b_a1[c]; w2c = W_a2[c]; }
#pragma unroll
      for (int r = 0; r < 4; ++r) {
        const float h = acc[nt][r] + b1c;
        s[r] += (h > 0.f ? h : 0.f) * w2c;
      }
    }
#pragma unroll
    for (int m = 1; m <= 8; m <<= 1) {
#pragma unroll
      for (int r = 0; r < 4; ++r) s[r] += __shfl_xor(s[r], m, 64);
    }
    if (m16 == 0) {
#pragma unroll
      for (int r = 0; r < 4; ++r) part[wave][quad * 4 + r] = s[r];
    }
  } else {
    const int c0 = wave * 80 - 160;  // Y col base for this wave
#pragma unroll
    for (int nt = 0; nt < 5; ++nt) {
#pragma unroll
      for (int r = 0; r < 4; ++r) {
        Y[(long)(rowBase + quad * 4 + r) * YCOLS + c0 + nt * 16 + m16] =
            acc[nt][r];
      }
    }
  }
  __syncthreads();
  if (tid < 16) attns[rowBase + tid] = part[0][tid] + part[1][tid] + b_a2[0];
}

// ---------------------------------------------------------------------------
// K2: one block per start token t.  Wave-specialized, ONE barrier.
//   FAST PATH (t < T-9, 4087/4096 blocks): ends[t*10+l] == t+l exactly, so
//   the end embed of span l IS pooled row o=l -> store it straight from the
//   register loaded in the pooled loop; start embed = row 0 from o==0.
//   This removes the 33 KB/block of redundant ee/e0 global re-reads
//   (-135 MB total) and interleaves NT stores with the FMA loop.
//   Tail blocks use the generic (round-1) path via sIE.
// ---------------------------------------------------------------------------
__global__ __launch_bounds__(256) void span_kernel(
    const float* __restrict__ embeds, const int* __restrict__ ends,
    const float* __restrict__ Y, const float* __restrict__ attns,
    const float* __restrict__ b_m1, const float* __restrict__ W_m2,
    const float* __restrict__ b_m2, float* __restrict__ g,
    float* __restrict__ scores) {
  __shared__ __align__(16) float Ys[L_SPAN][YCOLS];  // 19200 B
  __shared__ __align__(16) float wtsT[L_SPAN][12];   // [o][l], padded to 12
  __shared__ int sIE[L_SPAN];

  const int t = blockIdx.x;
  const int tid = threadIdx.x;
  const int wave = tid >> 6;
  const int lane = tid & 63;

  if (wave == 3) {
    for (int idx = lane; idx < L_SPAN * 120; idx += 64) {
      const int i = idx / 120, dd = idx - i * 120;
      const int r = min(t + i, T_TOK - 1);
      ((f32x4*)Ys)[idx] = ((const f32x4*)(Y + (long)r * YCOLS))[dd];
    }
  }
  if (tid < L_SPAN) {
    float a[L_SPAN];
#pragma unroll
    for (int o = 0; o < L_SPAN; ++o) a[o] = attns[min(t + o, T_TOK - 1)];
    const int ie = ends[t * L_SPAN + tid] - t;  // 0..9
    sIE[tid] = ie;
    float mx = a[0];
    for (int o = 1; o <= ie; ++o) mx = fmaxf(mx, a[o]);
    float den = 0.f;
    for (int o = 0; o <= ie; ++o) den += __expf(a[o] - mx);
    const float inv = 1.f / den;
#pragma unroll
    for (int o = 0; o < L_SPAN; ++o)
      wtsT[o][tid] = (o <= ie) ? __expf(a[o] - mx) * inv : 0.f;
  }
  __syncthreads();

  if (wave < 3) {
    const int d = tid;  // f32x4 column 0..191 (= floats d*4..d*4+3)
    f32x4 acc[L_SPAN];
#pragma unroll
    for (int l = 0; l < L_SPAN; ++l) acc[l] = (f32x4){0.f, 0.f, 0.f, 0.f};
    float* gbase = g + (long)t * L_SPAN * GDIM + d * 4;

    if (t < T_TOK - (L_SPAN - 1)) {
      // ---- fast path: end row of span l is exactly row l ----
#pragma unroll
      for (int o = 0; o < L_SPAN; ++o) {
        const f32x4 e = *(const f32x4*)(embeds + (long)(t + o) * D_DIM + d * 4);
        const f32x4 w0 = *(const f32x4*)&wtsT[o][0];
        const f32x4 w4 = *(const f32x4*)&wtsT[o][4];
        const f32x4 w8 = *(const f32x4*)&wtsT[o][8];
        acc[0] += e * w0.x; acc[1] += e * w0.y;
        acc[2] += e * w0.z; acc[3] += e * w0.w;
        acc[4] += e * w4.x; acc[5] += e * w4.y;
        acc[6] += e * w4.z; acc[7] += e * w4.w;
        acc[8] += e * w8.x; acc[9] += e * w8.y;
        // end embed of span l=o, straight from the register
        __builtin_nontemporal_store(e, (f32x4*)(gbase + (long)o * GDIM + D_DIM));
        if (o == 0) {
          // start embed (row 0) for all 10 spans
#pragma unroll
          for (int l = 0; l < L_SPAN; ++l)
            __builtin_nontemporal_store(e, (f32x4*)(gbase + (long)l * GDIM));
        }
      }
#pragma unroll
      for (int l = 0; l < L_SPAN; ++l)
        __builtin_nontemporal_store(acc[l],
                                    (f32x4*)(gbase + (long)l * GDIM + 2 * D_DIM));
    } else {
      // ---- generic tail path (last 9 tokens): clamped rows via sIE ----
#pragma unroll
      for (int o = 0; o < L_SPAN; ++o) {
        const int r = min(t + o, T_TOK - 1);
        const f32x4 e = *(const f32x4*)(embeds + (long)r * D_DIM + d * 4);
        const f32x4 w0 = *(const f32x4*)&wtsT[o][0];
        const f32x4 w4 = *(const f32x4*)&wtsT[o][4];
        const f32x4 w8 = *(const f32x4*)&wtsT[o][8];
        acc[0] += e * w0.x; acc[1] += e * w0.y;
        acc[2] += e * w0.z; acc[3] += e * w0.w;
        acc[4] += e * w4.x; acc[5] += e * w4.y;
        acc[6] += e * w4.z; acc[7] += e * w4.w;
        acc[8] += e * w8.x; acc[9] += e * w8.y;
      }
      const f32x4 e0 = *(const f32x4*)(embeds + (long)t * D_DIM + d * 4);
#pragma unroll
      for (int l = 0; l < L_SPAN; ++l) {
        float* go = gbase + (long)l * GDIM;
        const int re = t + sIE[l];
        const f32x4 ee = *(const f32x4*)(embeds + (long)re * D_DIM + d * 4);
        __builtin_nontemporal_store(e0, (f32x4*)go);
        __builtin_nontemporal_store(ee, (f32x4*)(go + D_DIM));
        __builtin_nontemporal_store(acc[l], (f32x4*)(go + 2 * D_DIM));
      }
    }
  } else {
    // span scores (wave 3 alone; Ys was written by this wave pre-barrier)
    const float bm2 = b_m2[0];
    for (int l = 0; l < L_SPAN; ++l) {
      const int ie = sIE[l];
      float wl[L_SPAN];
#pragma unroll
      for (int o = 0; o < L_SPAN; ++o) wl[o] = wtsT[o][l];
      float p = 0.f;
      for (int c = lane; c < H_HID; c += 64) {
        float h = Ys[0][c] + Ys[ie][160 + c] + b_m1[c];
#pragma unroll
        for (int o = 0; o < L_SPAN; ++o) h += wl[o] * Ys[o][320 + c];
        p += (h > 0.f ? h : 0.f) * W_m2[c];
      }
#pragma unroll
      for (int m = 1; m <= 32; m <<= 1) p += __shfl_xor(p, m, 64);
      if (lane == 0) scores[t * L_SPAN + l] = p + bm2;
    }
  }
}

// ---------------------------------------------------------------------------
extern "C" void kernel_launch(void* const* d_in, const int* in_sizes, int n_in,
                              void* d_out, int out_size, void* d_ws,
                              size_t ws_size, hipStream_t stream) {
  const float* embeds = (const float*)d_in[0];
  const int* ends = (const int*)d_in[2];
  const float* W_a1 = (const float*)d_in[3];
  const float* b_a1 = (const float*)d_in[4];
  const float* W_a2 = (const float*)d_in[5];
  const float* b_a2 = (const float*)d_in[6];
  const float* W_m1 = (const float*)d_in[7];
  const float* b_m1 = (const float*)d_in[8];
  const float* W_m2 = (const float*)d_in[9];
  const float* b_m2 = (const float*)d_in[10];

  char* ws = (char*)d_ws;
  bf16_t* Bp = (bf16_t*)ws;                    // 640*768*2  =   983,040 B
  float* Y = (float*)(ws + 983040);            // 4096*480*4 = 7,864,320 B
  float* attns = (float*)(ws + 983040 + 7864320);  // 16,384 B

  float* g_out = (float*)d_out;                     // [N][2304]
  float* score_out = g_out + (long)N_SPANS * GDIM;  // [N]

  prep_kernel<<<240, 256, 0, stream>>>(W_a1, W_m1, Bp);
  token_gemm_kernel<<<T_TOK / 16, 512, 0, stream>>>(embeds, Bp, Y, attns,
                                                    b_a1, W_a2, b_a2);
  span_kernel<<<T_TOK, 256, 0, stream>>>(embeds, ends, Y, attns, b_m1, W_m2,
                                         b_m2, g_out, score_out);
}